// Round 12
// baseline (549.125 us; speedup 1.0000x reference)
//
#include <hip/hip_runtime.h>
#include <cstdint>
#include <cstddef>

typedef _Float16 f16x8 __attribute__((ext_vector_type(8)));
typedef _Float16 f16x4 __attribute__((ext_vector_type(4)));
typedef float f32x4 __attribute__((ext_vector_type(4)));

__device__ __forceinline__ void gload_lds16(const _Float16* g, void* l) {
  __builtin_amdgcn_global_load_lds(
      (const __attribute__((address_space(1))) void*)(g),
      (__attribute__((address_space(3))) void*)(l), 16, 0, 0);
}

struct GDesc {
  const _Float16* A;
  const _Float16* B;
  void* C;
  int lda, ldb, ldc, nbm, nbn;
};

#define MFMA16(d, va, vb) \
  d = __builtin_amdgcn_mfma_f32_16x16x32_f16(va, vb, d, 0, 0, 0)

// ---------------------------------------------------------------------------
// Production gemmq — UNCHANGED from R10 (passing, ~860 TF/dispatch).
// ---------------------------------------------------------------------------
template <typename CT, bool MULTI>
__global__ __launch_bounds__(512, 2) void gemmq(
    GDesc d0, GDesc d1, GDesc d2,
    int inner, int nKT, int ksOff, size_t cSplit) {
  __shared__ __align__(16) char smem[131072];

  const int bid = blockIdx.x;
  const int gi  = bid / inner;
  int ib        = bid % inner;

  GDesc d = d0;
  if (MULTI) { if (gi == 1) d = d1; else if (gi == 2) d = d2; }
  const _Float16* A = d.A;
  const _Float16* B = d.B;
  CT* C = (CT*)d.C;
  if (!MULTI) {
    A += (size_t)gi * ksOff;
    B += (size_t)gi * ksOff;
    C += (size_t)gi * cSplit;
  }
  const int lda = d.lda, ldb = d.ldb, ldc = d.ldc, nbn = d.nbn;

  ib = (ib & 7) * (inner >> 3) + (ib >> 3);
  const int brow = (ib / nbn) << 8;
  const int bcol = (ib % nbn) << 8;

  const int tid = threadIdx.x;
  const int w   = tid >> 6;
  const int l   = tid & 63;
  const int wm  = w >> 2;
  const int wn  = w & 3;

  const int sRow = l >> 2;
  const int sCol = (((l & 3) ^ ((l >> 3) & 3)) << 3);
  const _Float16* gA0 = A + (size_t)(brow + (w << 4) + sRow) * lda + sCol;
  const _Float16* gA1 = A + (size_t)(brow + ((w + 8) << 4) + sRow) * lda + sCol;
  const _Float16* gB0 = B + (size_t)(bcol + (w << 4) + sRow) * ldb + sCol;
  const _Float16* gB1 = B + (size_t)(bcol + ((w + 8) << 4) + sRow) * ldb + sCol;

  const int axr = (l >> 1) & 3;
  const int fq  = ((l >> 4) ^ axr) << 4;
  const int aBase = (wm << 13) + ((l & 15) << 6) + fq;
  const int bBase = (wn << 12) + ((l & 15) << 6) + fq;

  f32x4 acc[8][4] = {};

  {
    char* nb = smem;
    gload_lds16(gA0 + 0,  nb + (w << 10));
    gload_lds16(gA1 + 0,  nb + ((w + 8) << 10));
    gload_lds16(gB0 + 0,  nb + 32768 + (w << 10));
    gload_lds16(gB1 + 0,  nb + 32768 + ((w + 8) << 10));
    gload_lds16(gA0 + 32, nb + 16384 + (w << 10));
    gload_lds16(gA1 + 32, nb + 16384 + ((w + 8) << 10));
    gload_lds16(gB0 + 32, nb + 49152 + (w << 10));
    gload_lds16(gB1 + 32, nb + 49152 + ((w + 8) << 10));
  }
  asm volatile("s_waitcnt vmcnt(4)" ::: "memory");
  __builtin_amdgcn_s_barrier();

  for (int t = 0; t < nKT; ++t) {
    const char* cb = smem + (t & 1) * 65536;
    char* nb = smem + ((t + 1) & 1) * 65536;
    const int jc = (t + 1 < nKT) ? t + 1 : nKT - 1;
    const int kof = jc * 64;

    f16x8 bf[4], a0f[4], a4f[4];

#pragma unroll
    for (int n = 0; n < 4; ++n) bf[n]  = *(const f16x8*)(cb + 32768 + bBase + (n << 10));
#pragma unroll
    for (int m = 0; m < 4; ++m) a0f[m] = *(const f16x8*)(cb + aBase + (m << 10));
    gload_lds16(gA0 + kof, nb + (w << 10));
    gload_lds16(gA1 + kof, nb + ((w + 8) << 10));
    __builtin_amdgcn_s_barrier();
    asm volatile("s_waitcnt lgkmcnt(0)" ::: "memory");
    __builtin_amdgcn_sched_barrier(0);
    __builtin_amdgcn_s_setprio(1);
#pragma unroll
    for (int m = 0; m < 4; ++m)
#pragma unroll
      for (int n = 0; n < 4; ++n) MFMA16(acc[m][n], a0f[m], bf[n]);
    __builtin_amdgcn_s_setprio(0);
    __builtin_amdgcn_s_barrier();

#pragma unroll
    for (int m = 0; m < 4; ++m) a4f[m] = *(const f16x8*)(cb + aBase + ((m + 4) << 10));
    gload_lds16(gB0 + kof, nb + 32768 + (w << 10));
    gload_lds16(gB1 + kof, nb + 32768 + ((w + 8) << 10));
    __builtin_amdgcn_s_barrier();
    asm volatile("s_waitcnt lgkmcnt(0)" ::: "memory");
    __builtin_amdgcn_sched_barrier(0);
    __builtin_amdgcn_s_setprio(1);
#pragma unroll
    for (int m = 0; m < 4; ++m)
#pragma unroll
      for (int n = 0; n < 4; ++n) MFMA16(acc[m + 4][n], a4f[m], bf[n]);
    __builtin_amdgcn_s_setprio(0);
    asm volatile("s_waitcnt vmcnt(4)" ::: "memory");
    __builtin_amdgcn_s_barrier();

#pragma unroll
    for (int n = 0; n < 4; ++n) bf[n]  = *(const f16x8*)(cb + 49152 + bBase + (n << 10));
#pragma unroll
    for (int m = 0; m < 4; ++m) a0f[m] = *(const f16x8*)(cb + 16384 + aBase + (m << 10));
    gload_lds16(gA0 + kof + 32, nb + 16384 + (w << 10));
    gload_lds16(gA1 + kof + 32, nb + 16384 + ((w + 8) << 10));
    __builtin_amdgcn_s_barrier();
    asm volatile("s_waitcnt lgkmcnt(0)" ::: "memory");
    __builtin_amdgcn_sched_barrier(0);
    __builtin_amdgcn_s_setprio(1);
#pragma unroll
    for (int m = 0; m < 4; ++m)
#pragma unroll
      for (int n = 0; n < 4; ++n) MFMA16(acc[m][n], a0f[m], bf[n]);
    __builtin_amdgcn_s_setprio(0);
    __builtin_amdgcn_s_barrier();

#pragma unroll
    for (int m = 0; m < 4; ++m) a4f[m] = *(const f16x8*)(cb + 16384 + aBase + ((m + 4) << 10));
    gload_lds16(gB0 + kof + 32, nb + 49152 + (w << 10));
    gload_lds16(gB1 + kof + 32, nb + 49152 + ((w + 8) << 10));
    __builtin_amdgcn_s_barrier();
    asm volatile("s_waitcnt lgkmcnt(0)" ::: "memory");
    __builtin_amdgcn_sched_barrier(0);
    __builtin_amdgcn_s_setprio(1);
#pragma unroll
    for (int m = 0; m < 4; ++m)
#pragma unroll
      for (int n = 0; n < 4; ++n) MFMA16(acc[m + 4][n], a4f[m], bf[n]);
    __builtin_amdgcn_s_setprio(0);
    asm volatile("s_waitcnt vmcnt(4)" ::: "memory");
    __builtin_amdgcn_s_barrier();
  }
  asm volatile("s_waitcnt vmcnt(0) lgkmcnt(0)" ::: "memory");

  const int crow0 = brow + (wm << 7) + ((l >> 4) << 2);
  const int ccol  = bcol + (wn << 6) + (l & 15);
#pragma unroll
  for (int m = 0; m < 8; ++m)
#pragma unroll
    for (int n = 0; n < 4; ++n)
#pragma unroll
      for (int jj = 0; jj < 4; ++jj)
        C[(size_t)(crow0 + (m << 4) + jj) * ldc + ccol + (n << 4)] = (CT)acc[m][n][jj];
}

// ---------------------------------------------------------------------------
// R12 ABLATION (nKT=96 so every variant ranks in the top-5 table; scratch out;
// OOB K-reads land inside ws — harmless garbage).
// VAR=0: full structure (steady-state tau probe)
// VAR=1: no VMEM staging (barriers + ds_read + lgkm + MFMA kept)
// VAR=3: MFMA + barriers only (no gload, no ds_read; frags kept live via asm)
// ---------------------------------------------------------------------------
template <int VAR>
__global__ __launch_bounds__(512, 2) void gemmabl(
    const _Float16* __restrict__ A, const _Float16* __restrict__ B,
    _Float16* __restrict__ C, int nKT) {
  __shared__ __align__(16) char smem[131072];
  constexpr bool STG = (VAR == 0);
  constexpr bool DSR = (VAR != 3);

  if (nKT == -1) ((volatile char*)smem)[0] = 1;  // keep LDS allocated

  int ib = blockIdx.x;
  ib = (ib & 7) * 32 + (ib >> 3);
  const int nbn = 16;
  const int brow = (ib / nbn) << 8;
  const int bcol = (ib % nbn) << 8;
  const int lda = 1024, ldb = 1024, ldc = 4096;

  const int tid = threadIdx.x;
  const int w   = tid >> 6;
  const int l   = tid & 63;
  const int wm  = w >> 2;
  const int wn  = w & 3;

  const int sRow = l >> 2;
  const int sCol = (((l & 3) ^ ((l >> 3) & 3)) << 3);
  const _Float16* gA0 = A + (size_t)(brow + (w << 4) + sRow) * lda + sCol;
  const _Float16* gA1 = A + (size_t)(brow + ((w + 8) << 4) + sRow) * lda + sCol;
  const _Float16* gB0 = B + (size_t)(bcol + (w << 4) + sRow) * ldb + sCol;
  const _Float16* gB1 = B + (size_t)(bcol + ((w + 8) << 4) + sRow) * ldb + sCol;

  const int axr = (l >> 1) & 3;
  const int fq  = ((l >> 4) ^ axr) << 4;
  const int aBase = (wm << 13) + ((l & 15) << 6) + fq;
  const int bBase = (wn << 12) + ((l & 15) << 6) + fq;

  f32x4 acc[8][4] = {};
  f16x8 bf[4], a0f[4], a4f[4];
#pragma unroll
  for (int i = 0; i < 4; ++i) { bf[i] = (f16x8)0; a0f[i] = (f16x8)0; a4f[i] = (f16x8)0; }

  if (STG) {
    char* nb = smem;
    gload_lds16(gA0 + 0,  nb + (w << 10));
    gload_lds16(gA1 + 0,  nb + ((w + 8) << 10));
    gload_lds16(gB0 + 0,  nb + 32768 + (w << 10));
    gload_lds16(gB1 + 0,  nb + 32768 + ((w + 8) << 10));
    gload_lds16(gA0 + 32, nb + 16384 + (w << 10));
    gload_lds16(gA1 + 32, nb + 16384 + ((w + 8) << 10));
    gload_lds16(gB0 + 32, nb + 49152 + (w << 10));
    gload_lds16(gB1 + 32, nb + 49152 + ((w + 8) << 10));
    asm volatile("s_waitcnt vmcnt(4)" ::: "memory");
  }
  __builtin_amdgcn_s_barrier();

  for (int t = 0; t < nKT; ++t) {
    const char* cb = smem + (t & 1) * 65536;
    char* nb = smem + ((t + 1) & 1) * 65536;
    const int jc = (t + 1 < nKT) ? t + 1 : nKT - 1;
    const int kof = jc * 64;

    // ph0
    if (DSR) {
#pragma unroll
      for (int n = 0; n < 4; ++n) bf[n]  = *(const f16x8*)(cb + 32768 + bBase + (n << 10));
#pragma unroll
      for (int m = 0; m < 4; ++m) a0f[m] = *(const f16x8*)(cb + aBase + (m << 10));
    }
    if (STG) { gload_lds16(gA0 + kof, nb + (w << 10)); gload_lds16(gA1 + kof, nb + ((w + 8) << 10)); }
    __builtin_amdgcn_s_barrier();
    if (DSR) asm volatile("s_waitcnt lgkmcnt(0)" ::: "memory");
    asm volatile("" :: "v"(bf[0]), "v"(a0f[0]));
    __builtin_amdgcn_sched_barrier(0);
    __builtin_amdgcn_s_setprio(1);
#pragma unroll
    for (int m = 0; m < 4; ++m)
#pragma unroll
      for (int n = 0; n < 4; ++n) MFMA16(acc[m][n], a0f[m], bf[n]);
    __builtin_amdgcn_s_setprio(0);
    __builtin_amdgcn_s_barrier();

    // ph1
    if (DSR) {
#pragma unroll
      for (int m = 0; m < 4; ++m) a4f[m] = *(const f16x8*)(cb + aBase + ((m + 4) << 10));
    }
    if (STG) { gload_lds16(gB0 + kof, nb + 32768 + (w << 10)); gload_lds16(gB1 + kof, nb + 32768 + ((w + 8) << 10)); }
    __builtin_amdgcn_s_barrier();
    if (DSR) asm volatile("s_waitcnt lgkmcnt(0)" ::: "memory");
    asm volatile("" :: "v"(a4f[0]));
    __builtin_amdgcn_sched_barrier(0);
    __builtin_amdgcn_s_setprio(1);
#pragma unroll
    for (int m = 0; m < 4; ++m)
#pragma unroll
      for (int n = 0; n < 4; ++n) MFMA16(acc[m + 4][n], a4f[m], bf[n]);
    __builtin_amdgcn_s_setprio(0);
    if (STG) asm volatile("s_waitcnt vmcnt(4)" ::: "memory");
    __builtin_amdgcn_s_barrier();

    // ph2
    if (DSR) {
#pragma unroll
      for (int n = 0; n < 4; ++n) bf[n]  = *(const f16x8*)(cb + 49152 + bBase + (n << 10));
#pragma unroll
      for (int m = 0; m < 4; ++m) a0f[m] = *(const f16x8*)(cb + 16384 + aBase + (m << 10));
    }
    if (STG) { gload_lds16(gA0 + kof + 32, nb + 16384 + (w << 10)); gload_lds16(gA1 + kof + 32, nb + 16384 + ((w + 8) << 10)); }
    __builtin_amdgcn_s_barrier();
    if (DSR) asm volatile("s_waitcnt lgkmcnt(0)" ::: "memory");
    asm volatile("" :: "v"(bf[0]), "v"(a0f[0]));
    __builtin_amdgcn_sched_barrier(0);
    __builtin_amdgcn_s_setprio(1);
#pragma unroll
    for (int m = 0; m < 4; ++m)
#pragma unroll
      for (int n = 0; n < 4; ++n) MFMA16(acc[m][n], a0f[m], bf[n]);
    __builtin_amdgcn_s_setprio(0);
    __builtin_amdgcn_s_barrier();

    // ph3
    if (DSR) {
#pragma unroll
      for (int m = 0; m < 4; ++m) a4f[m] = *(const f16x8*)(cb + 16384 + aBase + ((m + 4) << 10));
    }
    if (STG) { gload_lds16(gB0 + kof + 32, nb + 49152 + (w << 10)); gload_lds16(gB1 + kof + 32, nb + 49152 + ((w + 8) << 10)); }
    __builtin_amdgcn_s_barrier();
    if (DSR) asm volatile("s_waitcnt lgkmcnt(0)" ::: "memory");
    asm volatile("" :: "v"(a4f[0]));
    __builtin_amdgcn_sched_barrier(0);
    __builtin_amdgcn_s_setprio(1);
#pragma unroll
    for (int m = 0; m < 4; ++m)
#pragma unroll
      for (int n = 0; n < 4; ++n) MFMA16(acc[m + 4][n], a4f[m], bf[n]);
    __builtin_amdgcn_s_setprio(0);
    if (STG) asm volatile("s_waitcnt vmcnt(4)" ::: "memory");
    __builtin_amdgcn_s_barrier();
  }
  asm volatile("s_waitcnt vmcnt(0) lgkmcnt(0)" ::: "memory");

  const int crow0 = brow + (wm << 7) + ((l >> 4) << 2);
  const int ccol  = bcol + (wn << 6) + (l & 15);
#pragma unroll
  for (int m = 0; m < 8; ++m)
#pragma unroll
    for (int n = 0; n < 4; ++n)
#pragma unroll
      for (int jj = 0; jj < 4; ++jj)
        C[(size_t)(crow0 + (m << 4) + jj) * ldc + ccol + (n << 4)] = (_Float16)acc[m][n][jj];
}

// Row softmax: S fp16 -> P fp16 (internal f32).
__global__ __launch_bounds__(256) void softmax_rows(const _Float16* __restrict__ S,
                                                    _Float16* __restrict__ P,
                                                    int N) {
  __shared__ float buf[4096];
  __shared__ float red[8];
  const int row = blockIdx.x;
  const int tid = threadIdx.x;
  const int n8  = N >> 3;
  const int n4  = N >> 2;
  const f16x8* s8 = (const f16x8*)(S + (size_t)row * N);
  float4* b4 = (float4*)buf;

  float m = -3.4e38f;
  for (int i = tid; i < n8; i += 256) {
    f16x8 v = s8[i];
    float4 lo = { (float)v[0], (float)v[1], (float)v[2], (float)v[3] };
    float4 hi = { (float)v[4], (float)v[5], (float)v[6], (float)v[7] };
    b4[2 * i] = lo;
    b4[2 * i + 1] = hi;
    m = fmaxf(m, fmaxf(fmaxf(fmaxf(lo.x, lo.y), fmaxf(lo.z, lo.w)),
                       fmaxf(fmaxf(hi.x, hi.y), fmaxf(hi.z, hi.w))));
  }
  for (int off = 32; off > 0; off >>= 1) m = fmaxf(m, __shfl_xor(m, off));
  if ((tid & 63) == 0) red[tid >> 6] = m;
  __syncthreads();
  m = fmaxf(fmaxf(red[0], red[1]), fmaxf(red[2], red[3]));

  float sum = 0.f;
  for (int i = tid; i < n4; i += 256) {
    float4 v = b4[i];
    v.x = __expf(v.x - m); v.y = __expf(v.y - m);
    v.z = __expf(v.z - m); v.w = __expf(v.w - m);
    b4[i] = v;
    sum += (v.x + v.y) + (v.z + v.w);
  }
  for (int off = 32; off > 0; off >>= 1) sum += __shfl_xor(sum, off);
  if ((tid & 63) == 0) red[4 + (tid >> 6)] = sum;
  __syncthreads();
  sum = (red[4] + red[5]) + (red[6] + red[7]);
  const float inv = 1.f / sum;

  f16x4* p4 = (f16x4*)(P + (size_t)row * N);
  for (int i = tid; i < n4; i += 256) {
    float4 v = b4[i];
    f16x4 h = { (_Float16)(v.x * inv), (_Float16)(v.y * inv),
                (_Float16)(v.z * inv), (_Float16)(v.w * inv) };
    p4[i] = h;
  }
}

__global__ __launch_bounds__(256) void cast_all(
    const float* __restrict__ x1, const float* __restrict__ x2,
    const float* __restrict__ wq, const float* __restrict__ wk,
    const float* __restrict__ wv, _Float16* __restrict__ dst,
    int nx4, int nw4) {
  int i = blockIdx.x * 256 + threadIdx.x;
  const int total = 2 * nx4 + 3 * nw4;
  if (i >= total) return;
  const float* src;
  int off;
  if (i < nx4)           { src = x1; off = i; }
  else if (i < 2 * nx4)  { src = x2; off = i - nx4; }
  else {
    int j = i - 2 * nx4;
    if (j < nw4)           { src = wq; off = j; }
    else if (j < 2 * nw4)  { src = wk; off = j - nw4; }
    else                   { src = wv; off = j - 2 * nw4; }
  }
  float4 v = ((const float4*)src)[off];
  f16x4 h = { (_Float16)v.x, (_Float16)v.y, (_Float16)v.z, (_Float16)v.w };
  ((f16x4*)dst)[i] = h;
}

__global__ __launch_bounds__(256) void reduce4(const _Float16* __restrict__ p,
                                               float* __restrict__ out,
                                               int n4, size_t stride4) {
  int i = blockIdx.x * 256 + threadIdx.x;
  if (i >= n4) return;
  const f16x4* p4 = (const f16x4*)p;
  f16x4 a = p4[i];
  f16x4 b = p4[i + stride4];
  f16x4 c = p4[i + 2 * stride4];
  f16x4 d = p4[i + 3 * stride4];
  float4 r = { ((float)a[0] + (float)b[0]) + ((float)c[0] + (float)d[0]),
               ((float)a[1] + (float)b[1]) + ((float)c[1] + (float)d[1]),
               ((float)a[2] + (float)b[2]) + ((float)c[2] + (float)d[2]),
               ((float)a[3] + (float)b[3]) + ((float)c[3] + (float)d[3]) };
  ((float4*)out)[i] = r;
}

extern "C" void kernel_launch(void* const* d_in, const int* in_sizes, int n_in,
                              void* d_out, int out_size, void* d_ws, size_t ws_size,
                              hipStream_t stream) {
  const int D  = 1024;
  const int N1 = in_sizes[0] / D;
  const int N2 = in_sizes[1] / D;

  const float* x1 = (const float*)d_in[0];
  const float* x2 = (const float*)d_in[1];
  const float* Wq = (const float*)d_in[2];
  const float* Wk = (const float*)d_in[3];
  const float* Wv = (const float*)d_in[4];
  float* out = (float*)d_out;

  _Float16* x1h = (_Float16*)d_ws;
  _Float16* x2h = x1h + (size_t)N1 * D;
  _Float16* Wqh = x2h + (size_t)N2 * D;
  _Float16* Wkh = Wqh + (size_t)D * D;
  _Float16* Wvh = Wkh + (size_t)D * D;
  _Float16* Qh  = Wvh + (size_t)D * D;
  _Float16* Kh  = Qh  + (size_t)N1 * D;
  _Float16* Vt  = Kh  + (size_t)N2 * D;
  _Float16* P   = Vt  + (size_t)D * N2;
  _Float16* S   = P   + (size_t)N1 * N2;   // fp16 S; reused as PV partials
  _Float16* ablC = S  + (size_t)N1 * N2;   // 32MB dead scratch

  {
    int nx4 = N1 * D / 4;
    int nw4 = D * D / 4;
    int total = 2 * nx4 + 3 * nw4;
    cast_all<<<dim3((total + 255) / 256), 256, 0, stream>>>(
        x1, x2, Wq, Wk, Wv, x1h, nx4, nw4);
  }

  {
    GDesc dq = { x1h, Wqh, Qh, D, D, D, N1 / 256, D / 256 };
    GDesc dk = { x2h, Wkh, Kh, D, D, D, N2 / 256, D / 256 };
    GDesc dv = { Wvh, x2h, Vt, D, D, N2, D / 256, N2 / 256 };
    gemmq<_Float16, true><<<dim3(192), 512, 0, stream>>>(dq, dk, dv, 64, D / 64, 0, 0);
  }
  {
    GDesc dsd = { Qh, Kh, S, D, D, N2, N1 / 256, N2 / 256 };
    gemmq<_Float16, false><<<dim3(256), 512, 0, stream>>>(dsd, dsd, dsd, 256, D / 64, 0, 0);
  }
  softmax_rows<<<dim3(N1), 256, 0, stream>>>(S, P, N2);
  {
    GDesc dp = { P, Vt, S, N2, N2, D, N1 / 256, D / 256 };
    gemmq<_Float16, false><<<dim3(256), 512, 0, stream>>>(dp, dp, dp, 64, 1024 / 64, 1024,
                                                          (size_t)N1 * D);
  }
  reduce4<<<dim3((N1 * D / 4 + 255) / 256), 256, 0, stream>>>(
      S, out, N1 * D / 4, (size_t)N1 * D / 4);

  // ---- R12 ablations @ nKT=96 (each >=41us even at MFMA floor -> all rank)
  gemmabl<0><<<dim3(256), 512, 0, stream>>>(Qh, Kh, ablC, 96);  // steady-state tau
  gemmabl<1><<<dim3(256), 512, 0, stream>>>(Qh, Kh, ablC, 96);  // no VMEM staging
  gemmabl<3><<<dim3(256), 512, 0, stream>>>(Qh, Kh, ablC, 96);  // MFMA+barriers only
}

// Round 13
// 143.476 us; speedup vs baseline: 3.8273x; 3.8273x over previous
//
#include <hip/hip_runtime.h>
#include <cstdint>
#include <cstddef>

typedef _Float16 f16x8 __attribute__((ext_vector_type(8)));
typedef _Float16 f16x4 __attribute__((ext_vector_type(4)));
typedef float f32x4 __attribute__((ext_vector_type(4)));

__device__ __forceinline__ void gload_lds16(const _Float16* g, void* l) {
  __builtin_amdgcn_global_load_lds(
      (const __attribute__((address_space(1))) void*)(g),
      (__attribute__((address_space(3))) void*)(l), 16, 0, 0);
}

struct GDesc {
  const _Float16* A;
  const _Float16* B;
  void* C;
  int lda, ldb, ldc, nbm, nbn;
};

#define MFMA16(d, va, vb) \
  d = __builtin_amdgcn_mfma_f32_16x16x32_f16(va, vb, d, 0, 0, 0)

// ---------------------------------------------------------------------------
// Production gemmq (R10 build, final): 256x256 NT GEMM, BK=64 as two BK=32
// panels, 2 LDS buffers x 64KB, 8 waves (2M x 4N), 4 phases/K-tile
// { ds_reads ; 2 gloads ; barrier ; lgkmcnt(0) ; setprio+16 MFMA ;
//   [end ph1/ph3: vmcnt(4)] ; barrier }.
// Zero-conflict XOR swizzle (SQ_LDS_BANK_CONFLICT=0, R2-R12).
// Measured ~860 TF/dispatch at K=1024 = m248's documented template ceiling
// (848 TF) for this K-depth. R12 ablation: tau_steady=1.886us/tile
// (MFMA+barriers ~= floor; ds_reads +0.2; staging +0.6), fixed 9.6us/dispatch
// (C-write at BW roof + cold prologue).
// ---------------------------------------------------------------------------
template <typename CT, bool MULTI>
__global__ __launch_bounds__(512, 2) void gemmq(
    GDesc d0, GDesc d1, GDesc d2,
    int inner, int nKT, int ksOff, size_t cSplit) {
  __shared__ __align__(16) char smem[131072];

  const int bid = blockIdx.x;
  const int gi  = bid / inner;
  int ib        = bid % inner;

  GDesc d = d0;
  if (MULTI) { if (gi == 1) d = d1; else if (gi == 2) d = d2; }
  const _Float16* A = d.A;
  const _Float16* B = d.B;
  CT* C = (CT*)d.C;
  if (!MULTI) {
    A += (size_t)gi * ksOff;
    B += (size_t)gi * ksOff;
    C += (size_t)gi * cSplit;
  }
  const int lda = d.lda, ldb = d.ldb, ldc = d.ldc, nbn = d.nbn;

  ib = (ib & 7) * (inner >> 3) + (ib >> 3);
  const int brow = (ib / nbn) << 8;
  const int bcol = (ib % nbn) << 8;

  const int tid = threadIdx.x;
  const int w   = tid >> 6;
  const int l   = tid & 63;
  const int wm  = w >> 2;
  const int wn  = w & 3;

  const int sRow = l >> 2;
  const int sCol = (((l & 3) ^ ((l >> 3) & 3)) << 3);
  const _Float16* gA0 = A + (size_t)(brow + (w << 4) + sRow) * lda + sCol;
  const _Float16* gA1 = A + (size_t)(brow + ((w + 8) << 4) + sRow) * lda + sCol;
  const _Float16* gB0 = B + (size_t)(bcol + (w << 4) + sRow) * ldb + sCol;
  const _Float16* gB1 = B + (size_t)(bcol + ((w + 8) << 4) + sRow) * ldb + sCol;

  const int axr = (l >> 1) & 3;
  const int fq  = ((l >> 4) ^ axr) << 4;
  const int aBase = (wm << 13) + ((l & 15) << 6) + fq;
  const int bBase = (wn << 12) + ((l & 15) << 6) + fq;

  f32x4 acc[8][4] = {};

  {
    char* nb = smem;
    gload_lds16(gA0 + 0,  nb + (w << 10));
    gload_lds16(gA1 + 0,  nb + ((w + 8) << 10));
    gload_lds16(gB0 + 0,  nb + 32768 + (w << 10));
    gload_lds16(gB1 + 0,  nb + 32768 + ((w + 8) << 10));
    gload_lds16(gA0 + 32, nb + 16384 + (w << 10));
    gload_lds16(gA1 + 32, nb + 16384 + ((w + 8) << 10));
    gload_lds16(gB0 + 32, nb + 49152 + (w << 10));
    gload_lds16(gB1 + 32, nb + 49152 + ((w + 8) << 10));
  }
  asm volatile("s_waitcnt vmcnt(4)" ::: "memory");
  __builtin_amdgcn_s_barrier();

  for (int t = 0; t < nKT; ++t) {
    const char* cb = smem + (t & 1) * 65536;
    char* nb = smem + ((t + 1) & 1) * 65536;
    const int jc = (t + 1 < nKT) ? t + 1 : nKT - 1;
    const int kof = jc * 64;

    f16x8 bf[4], a0f[4], a4f[4];

#pragma unroll
    for (int n = 0; n < 4; ++n) bf[n]  = *(const f16x8*)(cb + 32768 + bBase + (n << 10));
#pragma unroll
    for (int m = 0; m < 4; ++m) a0f[m] = *(const f16x8*)(cb + aBase + (m << 10));
    gload_lds16(gA0 + kof, nb + (w << 10));
    gload_lds16(gA1 + kof, nb + ((w + 8) << 10));
    __builtin_amdgcn_s_barrier();
    asm volatile("s_waitcnt lgkmcnt(0)" ::: "memory");
    __builtin_amdgcn_sched_barrier(0);
    __builtin_amdgcn_s_setprio(1);
#pragma unroll
    for (int m = 0; m < 4; ++m)
#pragma unroll
      for (int n = 0; n < 4; ++n) MFMA16(acc[m][n], a0f[m], bf[n]);
    __builtin_amdgcn_s_setprio(0);
    __builtin_amdgcn_s_barrier();

#pragma unroll
    for (int m = 0; m < 4; ++m) a4f[m] = *(const f16x8*)(cb + aBase + ((m + 4) << 10));
    gload_lds16(gB0 + kof, nb + 32768 + (w << 10));
    gload_lds16(gB1 + kof, nb + 32768 + ((w + 8) << 10));
    __builtin_amdgcn_s_barrier();
    asm volatile("s_waitcnt lgkmcnt(0)" ::: "memory");
    __builtin_amdgcn_sched_barrier(0);
    __builtin_amdgcn_s_setprio(1);
#pragma unroll
    for (int m = 0; m < 4; ++m)
#pragma unroll
      for (int n = 0; n < 4; ++n) MFMA16(acc[m + 4][n], a4f[m], bf[n]);
    __builtin_amdgcn_s_setprio(0);
    asm volatile("s_waitcnt vmcnt(4)" ::: "memory");
    __builtin_amdgcn_s_barrier();

#pragma unroll
    for (int n = 0; n < 4; ++n) bf[n]  = *(const f16x8*)(cb + 49152 + bBase + (n << 10));
#pragma unroll
    for (int m = 0; m < 4; ++m) a0f[m] = *(const f16x8*)(cb + 16384 + aBase + (m << 10));
    gload_lds16(gA0 + kof + 32, nb + 16384 + (w << 10));
    gload_lds16(gA1 + kof + 32, nb + 16384 + ((w + 8) << 10));
    __builtin_amdgcn_s_barrier();
    asm volatile("s_waitcnt lgkmcnt(0)" ::: "memory");
    __builtin_amdgcn_sched_barrier(0);
    __builtin_amdgcn_s_setprio(1);
#pragma unroll
    for (int m = 0; m < 4; ++m)
#pragma unroll
      for (int n = 0; n < 4; ++n) MFMA16(acc[m][n], a0f[m], bf[n]);
    __builtin_amdgcn_s_setprio(0);
    __builtin_amdgcn_s_barrier();

#pragma unroll
    for (int m = 0; m < 4; ++m) a4f[m] = *(const f16x8*)(cb + 16384 + aBase + ((m + 4) << 10));
    gload_lds16(gB0 + kof + 32, nb + 49152 + (w << 10));
    gload_lds16(gB1 + kof + 32, nb + 49152 + ((w + 8) << 10));
    __builtin_amdgcn_s_barrier();
    asm volatile("s_waitcnt lgkmcnt(0)" ::: "memory");
    __builtin_amdgcn_sched_barrier(0);
    __builtin_amdgcn_s_setprio(1);
#pragma unroll
    for (int m = 0; m < 4; ++m)
#pragma unroll
      for (int n = 0; n < 4; ++n) MFMA16(acc[m + 4][n], a4f[m], bf[n]);
    __builtin_amdgcn_s_setprio(0);
    asm volatile("s_waitcnt vmcnt(4)" ::: "memory");
    __builtin_amdgcn_s_barrier();
  }
  asm volatile("s_waitcnt vmcnt(0) lgkmcnt(0)" ::: "memory");

  const int crow0 = brow + (wm << 7) + ((l >> 4) << 2);
  const int ccol  = bcol + (wn << 6) + (l & 15);
#pragma unroll
  for (int m = 0; m < 8; ++m)
#pragma unroll
    for (int n = 0; n < 4; ++n)
#pragma unroll
      for (int jj = 0; jj < 4; ++jj)
        C[(size_t)(crow0 + (m << 4) + jj) * ldc + ccol + (n << 4)] = (CT)acc[m][n][jj];
}

// Row softmax: S fp16 -> P fp16 (internal f32). ~6.4 TB/s (BW roof).
__global__ __launch_bounds__(256) void softmax_rows(const _Float16* __restrict__ S,
                                                    _Float16* __restrict__ P,
                                                    int N) {
  __shared__ float buf[4096];
  __shared__ float red[8];
  const int row = blockIdx.x;
  const int tid = threadIdx.x;
  const int n8  = N >> 3;
  const int n4  = N >> 2;
  const f16x8* s8 = (const f16x8*)(S + (size_t)row * N);
  float4* b4 = (float4*)buf;

  float m = -3.4e38f;
  for (int i = tid; i < n8; i += 256) {
    f16x8 v = s8[i];
    float4 lo = { (float)v[0], (float)v[1], (float)v[2], (float)v[3] };
    float4 hi = { (float)v[4], (float)v[5], (float)v[6], (float)v[7] };
    b4[2 * i] = lo;
    b4[2 * i + 1] = hi;
    m = fmaxf(m, fmaxf(fmaxf(fmaxf(lo.x, lo.y), fmaxf(lo.z, lo.w)),
                       fmaxf(fmaxf(hi.x, hi.y), fmaxf(hi.z, hi.w))));
  }
  for (int off = 32; off > 0; off >>= 1) m = fmaxf(m, __shfl_xor(m, off));
  if ((tid & 63) == 0) red[tid >> 6] = m;
  __syncthreads();
  m = fmaxf(fmaxf(red[0], red[1]), fmaxf(red[2], red[3]));

  float sum = 0.f;
  for (int i = tid; i < n4; i += 256) {
    float4 v = b4[i];
    v.x = __expf(v.x - m); v.y = __expf(v.y - m);
    v.z = __expf(v.z - m); v.w = __expf(v.w - m);
    b4[i] = v;
    sum += (v.x + v.y) + (v.z + v.w);
  }
  for (int off = 32; off > 0; off >>= 1) sum += __shfl_xor(sum, off);
  if ((tid & 63) == 0) red[4 + (tid >> 6)] = sum;
  __syncthreads();
  sum = (red[4] + red[5]) + (red[6] + red[7]);
  const float inv = 1.f / sum;

  f16x4* p4 = (f16x4*)(P + (size_t)row * N);
  for (int i = tid; i < n4; i += 256) {
    float4 v = b4[i];
    f16x4 h = { (_Float16)(v.x * inv), (_Float16)(v.y * inv),
                (_Float16)(v.z * inv), (_Float16)(v.w * inv) };
    p4[i] = h;
  }
}

// All 5 f32->fp16 casts in one dispatch (~7 TB/s, BW roof).
__global__ __launch_bounds__(256) void cast_all(
    const float* __restrict__ x1, const float* __restrict__ x2,
    const float* __restrict__ wq, const float* __restrict__ wk,
    const float* __restrict__ wv, _Float16* __restrict__ dst,
    int nx4, int nw4) {
  int i = blockIdx.x * 256 + threadIdx.x;
  const int total = 2 * nx4 + 3 * nw4;
  if (i >= total) return;
  const float* src;
  int off;
  if (i < nx4)           { src = x1; off = i; }
  else if (i < 2 * nx4)  { src = x2; off = i - nx4; }
  else {
    int j = i - 2 * nx4;
    if (j < nw4)           { src = wq; off = j; }
    else if (j < 2 * nw4)  { src = wk; off = j - nw4; }
    else                   { src = wv; off = j - 2 * nw4; }
  }
  float4 v = ((const float4*)src)[off];
  f16x4 h = { (_Float16)v.x, (_Float16)v.y, (_Float16)v.z, (_Float16)v.w };
  ((f16x4*)dst)[i] = h;
}

// out[i] = sum of 4 fp16 split-K partials (deterministic, f32 accumulate)
__global__ __launch_bounds__(256) void reduce4(const _Float16* __restrict__ p,
                                               float* __restrict__ out,
                                               int n4, size_t stride4) {
  int i = blockIdx.x * 256 + threadIdx.x;
  if (i >= n4) return;
  const f16x4* p4 = (const f16x4*)p;
  f16x4 a = p4[i];
  f16x4 b = p4[i + stride4];
  f16x4 c = p4[i + 2 * stride4];
  f16x4 d = p4[i + 3 * stride4];
  float4 r = { ((float)a[0] + (float)b[0]) + ((float)c[0] + (float)d[0]),
               ((float)a[1] + (float)b[1]) + ((float)c[1] + (float)d[1]),
               ((float)a[2] + (float)b[2]) + ((float)c[2] + (float)d[2]),
               ((float)a[3] + (float)b[3]) + ((float)c[3] + (float)d[3]) };
  ((float4*)out)[i] = r;
}

extern "C" void kernel_launch(void* const* d_in, const int* in_sizes, int n_in,
                              void* d_out, int out_size, void* d_ws, size_t ws_size,
                              hipStream_t stream) {
  const int D  = 1024;
  const int N1 = in_sizes[0] / D;
  const int N2 = in_sizes[1] / D;

  const float* x1 = (const float*)d_in[0];
  const float* x2 = (const float*)d_in[1];
  const float* Wq = (const float*)d_in[2];
  const float* Wk = (const float*)d_in[3];
  const float* Wv = (const float*)d_in[4];
  float* out = (float*)d_out;

  _Float16* x1h = (_Float16*)d_ws;
  _Float16* x2h = x1h + (size_t)N1 * D;
  _Float16* Wqh = x2h + (size_t)N2 * D;
  _Float16* Wkh = Wqh + (size_t)D * D;
  _Float16* Wvh = Wkh + (size_t)D * D;
  _Float16* Qh  = Wvh + (size_t)D * D;
  _Float16* Kh  = Qh  + (size_t)N1 * D;
  _Float16* Vt  = Kh  + (size_t)N2 * D;   // Vt[j,i] = V[i,j]
  _Float16* P   = Vt  + (size_t)D * N2;
  _Float16* S   = P   + (size_t)N1 * N2;  // fp16 S; reused as PV partials

  {
    int nx4 = N1 * D / 4;
    int nw4 = D * D / 4;
    int total = 2 * nx4 + 3 * nw4;
    cast_all<<<dim3((total + 255) / 256), 256, 0, stream>>>(
        x1, x2, Wq, Wk, Wv, x1h, nx4, nw4);
  }

  // Fused QKV projections: one 192-block dispatch (192 natural 256^2 tiles).
  {
    GDesc dq = { x1h, Wqh, Qh, D, D, D, N1 / 256, D / 256 };
    GDesc dk = { x2h, Wkh, Kh, D, D, D, N2 / 256, D / 256 };
    GDesc dv = { Wvh, x2h, Vt, D, D, N2, D / 256, N2 / 256 };
    gemmq<_Float16, true><<<dim3(192), 512, 0, stream>>>(dq, dk, dv, 64, D / 64, 0, 0);
  }
  // S = Q K^T [4096x4096] fp16, grid 256 (1 block/CU)
  {
    GDesc dsd = { Qh, Kh, S, D, D, N2, N1 / 256, N2 / 256 };
    gemmq<_Float16, false><<<dim3(256), 512, 0, stream>>>(dsd, dsd, dsd, 256, D / 64, 0, 0);
  }
  // P = softmax(S)
  softmax_rows<<<dim3(N1), 256, 0, stream>>>(S, P, N2);
  // PV split-K=4: fp16 partial[s] = P[:, s*1024:+1024] @ Vt[:, s*1024:+1024]^T
  {
    GDesc dp = { P, Vt, S, N2, N2, D, N1 / 256, D / 256 };
    gemmq<_Float16, false><<<dim3(256), 512, 0, stream>>>(dp, dp, dp, 64, 1024 / 64, 1024,
                                                          (size_t)N1 * D);
  }
  reduce4<<<dim3((N1 * D / 4 + 255) / 256), 256, 0, stream>>>(
      S, out, N1 * D / 4, (size_t)N1 * D / 4);
}